// Round 7
// baseline (497.085 us; speedup 1.0000x reference)
//
#include <hip/hip_runtime.h>
#include <math.h>

#define BATCH 8
#define NPTS 2048
#define KF 1024
#define PTB 128   // points per block: 4 waves x 32 (2 ptiles of 16 per wave)

typedef _Float16 f16x8 __attribute__((ext_vector_type(8)));
typedef float f32x4 __attribute__((ext_vector_type(4)));

// 16x16x32 layouts HW-verified (m89/m91/m97/m120); dtype-independent:
//  A: lane holds A[m=lane&15][k=(lane>>4)*8+j]
//  B: lane holds B[k=(lane>>4)*8+j][n=lane&15]
//  C/D: lane,reg holds C[row=(lane>>4)*4+reg][col=lane&15]
#define MFMA16(a,b,c) __builtin_amdgcn_mfma_f32_16x16x32_f16((a),(b),(c),0,0,0)

#define FSCALE 256.0f
#define INV16  (1.0f/65536.0f)

// fp16 2-way split of (x*256): hi+lo represents xs to ~2^-22 relative; all 4
// cross products kept -> f32-equivalent GEMM precision after GN amplification.
__device__ __forceinline__ void split_f16s(float x, _Float16& hi, _Float16& lo) {
  float xs = x * FSCALE;
  hi = (_Float16)xs;
  lo = (_Float16)(xs - (float)hi);
}

// ---------------- misc device helpers ----------------
__device__ __forceinline__ void mat3mul(const float* A, const float* Bm, float* C) {
#pragma unroll
  for (int i = 0; i < 3; ++i)
#pragma unroll
    for (int j = 0; j < 3; ++j)
      C[i*3+j] = A[i*3+0]*Bm[0*3+j] + A[i*3+1]*Bm[1*3+j] + A[i*3+2]*Bm[2*3+j];
}

__device__ void se3_exp_dev(const float* x, float* R, float* p) {
  float wx = x[0], wy = x[1], wz = x[2];
  float vx = x[3], vy = x[4], vz = x[5];
  float t2 = wx*wx + wy*wy + wz*wz;
  float t = sqrtf(t2);
  float A, Bc, Cc;
  if (t < 1e-6f) {
    A  = 1.f - t2*(1.f/6.f);
    Bc = 0.5f - t2*(1.f/24.f);
    Cc = (1.f/6.f) - t2*(1.f/120.f);
  } else {
    float s = sinf(t), c = cosf(t);
    A  = s / t;
    Bc = (1.f - c) / t2;
    Cc = (t - s) / (t2 * t);
  }
  float W[9]  = {0.f, -wz, wy,  wz, 0.f, -wx,  -wy, wx, 0.f};
  float W2[9];
  mat3mul(W, W, W2);
#pragma unroll
  for (int i = 0; i < 9; ++i) {
    float I = (i == 0 || i == 4 || i == 8) ? 1.f : 0.f;
    R[i] = I + A*W[i] + Bc*W2[i];
  }
  float V[9];
#pragma unroll
  for (int i = 0; i < 9; ++i) {
    float I = (i == 0 || i == 4 || i == 8) ? 1.f : 0.f;
    V[i] = I + Bc*W[i] + Cc*W2[i];
  }
  p[0] = V[0]*vx + V[1]*vy + V[2]*vz;
  p[1] = V[3]*vx + V[4]*vy + V[5]*vz;
  p[2] = V[6]*vx + V[7]*vy + V[8]*vz;
}

__device__ __forceinline__ void atomicMaxFloat(float* addr, float val) {
  if (__float_as_uint(val) >> 31) {
    atomicMin((unsigned int*)addr, __float_as_uint(val));
  } else {
    atomicMax((int*)addr, __float_as_int(val));
  }
}

// ---------------- small kernels (verified) ----------------
__global__ void means_kernel(const float* __restrict__ tgt, const float* __restrict__ src,
                             float* __restrict__ mean_tgt, float* __restrict__ mean_src) {
  int which = blockIdx.x & 1, b = blockIdx.x >> 1;
  const float* p = (which ? src : tgt) + (size_t)b*NPTS*3;
  float* m = (which ? mean_src : mean_tgt) + b*3;
  int t = threadIdx.x;
  float s0 = 0.f, s1 = 0.f, s2 = 0.f;
  for (int i = t; i < NPTS; i += 256) {
    s0 += p[i*3+0]; s1 += p[i*3+1]; s2 += p[i*3+2];
  }
  __shared__ float red[256][3];
  red[t][0] = s0; red[t][1] = s1; red[t][2] = s2;
  __syncthreads();
  for (int s = 128; s > 0; s >>= 1) {
    if (t < s) { red[t][0] += red[t+s][0]; red[t][1] += red[t+s][1]; red[t][2] += red[t+s][2]; }
    __syncthreads();
  }
  if (t == 0) {
    m[0] = red[0][0] * (1.f/NPTS);
    m[1] = red[0][1] * (1.f/NPTS);
    m[2] = red[0][2] * (1.f/NPTS);
  }
}

__global__ void setup_kernel(const float* __restrict__ dt, const float* __restrict__ W1,
                             const float* __restrict__ b1, const float* __restrict__ igt_twist,
                             float* __restrict__ feats, float* __restrict__ f1,
                             float* __restrict__ W1eff7, float* __restrict__ b1eff7,
                             float* __restrict__ W1effL, float* __restrict__ b1effL,
                             float* __restrict__ g_buf, float* __restrict__ igt_inv,
                             float* __restrict__ loss_out) {
  int t = threadIdx.x;
  for (int i = t; i < BATCH*7*KF; i += 256) feats[i] = -INFINITY;
  for (int i = t; i < BATCH*KF;   i += 256) f1[i]    = -INFINITY;
  for (int i = t; i < BATCH*192;  i += 256) W1effL[i] = W1[i % 192];
  for (int i = t; i < BATCH*64;   i += 256) b1effL[i] = b1[i & 63];
  if (t < 192) W1eff7[t] = W1[t];
  if (t < 64)  b1eff7[t] = b1[t];
  if (t < BATCH*16) {
    int i = t & 15;
    g_buf[t] = (i == 0 || i == 5 || i == 10 || i == 15) ? 1.f : 0.f;
  }
  if (t == 0) *loss_out = 0.f;
  if (t < 6) {
    float tw[6] = {0.f,0.f,0.f,0.f,0.f,0.f};
    tw[t] = -dt[t];
    float R[9], tr[3];
    se3_exp_dev(tw, R, tr);
    float* Wd = W1eff7 + (t+1)*192;
    for (int d = 0; d < 3; ++d)
      for (int c = 0; c < 64; ++c)
        Wd[d*64+c] = R[0*3+d]*W1[c] + R[1*3+d]*W1[64+c] + R[2*3+d]*W1[128+c];
    float* bd = b1eff7 + (t+1)*64;
    for (int c = 0; c < 64; ++c)
      bd[c] = b1[c] + tr[0]*W1[c] + tr[1]*W1[64+c] + tr[2]*W1[128+c];
  }
  if (t >= 32 && t < 32+BATCH) {
    int b = t - 32;
    float R[9], tr[3];
    se3_exp_dev(igt_twist + b*6, R, tr);
    float* inv = igt_inv + b*12;
    for (int r = 0; r < 3; ++r) {
      inv[r*4+0] = R[0*3+r];
      inv[r*4+1] = R[1*3+r];
      inv[r*4+2] = R[2*3+r];
      inv[r*4+3] = -(R[0*3+r]*tr[0] + R[1*3+r]*tr[1] + R[2*3+r]*tr[2]);
    }
  }
}

// ---------------- weight packs ----------------
// W3: contiguous 8 KB per nt tile: [nt][level][ks3][lane][j], so a tile is a
// linear 4096-f16 block that stages into LDS with a straight 16 B/thread copy.
// B element (k,n) -> lane = ((k&31)>>3)*16 + (n&15), j = k&7; ks3 = k>>5.
__global__ void pack_w3_kernel(const float* __restrict__ W3, _Float16* __restrict__ P) {
  int i = blockIdx.x*256 + threadIdx.x;   // 128*1024
  int k = i >> 10, n = i & 1023;
  _Float16 hi, lo;
  split_f16s(W3[i], hi, lo);
  int nt = n >> 4, col = n & 15;
  int ks3 = k >> 5, rr = k & 31;
  int lane = (rr >> 3)*16 + col, jj = rr & 7;
  size_t base = (size_t)nt*4096;
  P[base + ((0*4 + ks3)*64 + lane)*8 + jj] = hi;
  P[base + ((1*4 + ks3)*64 + lane)*8 + jj] = lo;
}

__global__ void pack_w2_kernel(const float* __restrict__ W2,
                               _Float16* __restrict__ H, _Float16* __restrict__ L) {
  int i = blockIdx.x*256 + threadIdx.x;   // 64*128
  int k = i >> 7, n = i & 127;
  _Float16 hi, lo;
  split_f16s(W2[i], hi, lo);
  int nt2 = n >> 4, col = n & 15;
  int ks = k >> 5, rr = k & 31;
  int lane = (rr >> 3)*16 + col, jj = rr & 7;
  int dst = ((nt2*2 + ks)*64 + lane)*8 + jj;
  H[dst] = hi; L[dst] = lo;
}

// ---------------- MFMA encode ----------------
__device__ __forceinline__ f32x4 zero4() {
  f32x4 z; z[0]=0.f; z[1]=0.f; z[2]=0.f; z[3]=0.f; return z;
}

__device__ __forceinline__ void l3_body(
    const f16x8 (&Ah)[2][4], const f16x8 (&Al)[2][4],
    const f16x8 (&B)[2][4],
    int nt, int l, const float* __restrict__ b3, float* __restrict__ outp) {
  f32x4 a[2] = {zero4(), zero4()};
#pragma unroll
  for (int ks = 0; ks < 4; ++ks) {
#pragma unroll
    for (int p = 0; p < 2; ++p) a[p] = MFMA16(Al[p][ks], B[1][ks], a[p]);  // l*l
#pragma unroll
    for (int p = 0; p < 2; ++p) a[p] = MFMA16(Al[p][ks], B[0][ks], a[p]);  // l*h
#pragma unroll
    for (int p = 0; p < 2; ++p) a[p] = MFMA16(Ah[p][ks], B[1][ks], a[p]);  // h*l
#pragma unroll
    for (int p = 0; p < 2; ++p) a[p] = MFMA16(Ah[p][ks], B[0][ks], a[p]);  // h*h
  }
  float mx = -INFINITY;
#pragma unroll
  for (int p = 0; p < 2; ++p)
#pragma unroll
    for (int r = 0; r < 4; ++r) mx = fmaxf(mx, a[p][r]);
  mx = fmaxf(mx, __shfl_xor(mx, 16, 64));
  mx = fmaxf(mx, __shfl_xor(mx, 32, 64));
  if (l < 16) {
    int feat = nt*16 + l;
    atomicMaxFloat(outp + feat, mx*INV16 + b3[feat]);
  }
}

// grid: (NPTS/PTB, NJ*FG, BATCH); 256 threads = 4 waves x 32 points.
// Layer-3 B tiles staged once per BLOCK into LDS (double-buffered, one barrier
// per tile) and shared by all 4 waves: 4x fewer global B loads than R5, and
// tile k+1's staging latency hides under tile k's 128 block-MFMAs.
__global__ __launch_bounds__(256, 3) void encode_mfma(
    const float* __restrict__ pts, const float* __restrict__ mean,
    const float* __restrict__ W1e, const float* __restrict__ b1e,
    const _Float16* __restrict__ W2h, const _Float16* __restrict__ W2l,
    const _Float16* __restrict__ W3p,
    const float* __restrict__ b2, const float* __restrict__ b3,
    float* __restrict__ out, int NJ, int FG, int per_batch) {
  const int t = threadIdx.x;
  const int w = t >> 6, l = t & 63;
  const int lm = l & 15, q = l >> 4;
  const int pblk = blockIdx.x;
  const int j = blockIdx.y / FG, fg = blockIdx.y % FG;
  const int b = blockIdx.z;
  const int widx = per_batch ? b : j;
  const int NT_PER = 64 / FG;
  const int nt0 = fg * NT_PER;

  // 32 KB: preamble = per-wave relayout scratch (w*4096); l3 = B double buffer
  __shared__ __align__(16) _Float16 smem[16384];

  // ---- the wave's 32 centered points: ptile p in {0,1}, row lm ----
  const int ptbase = pblk*PTB + w*32;
  float mx0 = mean[b*3+0], my0 = mean[b*3+1], mz0 = mean[b*3+2];
  float px[2], py[2], pz[2];
#pragma unroll
  for (int p = 0; p < 2; ++p) {
    const float* pp = pts + ((size_t)b*NPTS + ptbase + p*16 + lm)*3;
    px[p] = pp[0] - mx0; py[p] = pp[1] - my0; pz[p] = pp[2] - mz0;
  }

  const float* w1 = W1e + widx*192;
  const float* bb1 = b1e + widx*64;

  f16x8 A3h[2][4], A3l[2][4];
  _Float16* scr = smem + w*4096;   // per-wave: [level][2048]

#pragma unroll
  for (int p = 0; p < 2; ++p) {
    // ---- layer 1: A2 fragments (this ptile); lane: point lm, channels ks*32 + q*8 + jj ----
    f16x8 A2h[2], A2l[2];
#pragma unroll
    for (int ks = 0; ks < 2; ++ks) {
      const int c0 = ks*32 + q*8;
      float wa[8], wb[8], wc[8], bv[8];
      *(float4*)&wa[0] = *(const float4*)(w1 + c0);
      *(float4*)&wa[4] = *(const float4*)(w1 + c0 + 4);
      *(float4*)&wb[0] = *(const float4*)(w1 + 64 + c0);
      *(float4*)&wb[4] = *(const float4*)(w1 + 64 + c0 + 4);
      *(float4*)&wc[0] = *(const float4*)(w1 + 128 + c0);
      *(float4*)&wc[4] = *(const float4*)(w1 + 128 + c0 + 4);
      *(float4*)&bv[0] = *(const float4*)(bb1 + c0);
      *(float4*)&bv[4] = *(const float4*)(bb1 + c0 + 4);
#pragma unroll
      for (int jj = 0; jj < 8; ++jj) {
        float h = fmaf(px[p], wa[jj], fmaf(py[p], wb[jj], fmaf(pz[p], wc[jj], bv[jj])));
        h = fmaxf(h, 0.f);
        _Float16 hi, lo;
        split_f16s(h, hi, lo);
        A2h[ks][jj] = hi; A2l[ks][jj] = lo;
      }
    }
    // ---- layer 2: 8 ntiles of 16 features; 4-product accumulate; relayout via scr ----
#pragma unroll
    for (int nt2 = 0; nt2 < 8; ++nt2) {
      f32x4 acc = zero4();
#pragma unroll
      for (int ks = 0; ks < 2; ++ks) {
        const int base = ((nt2*2 + ks)*64 + l)*8;
        const f16x8 Bh = *(const f16x8*)(W2h + base);
        const f16x8 Bl = *(const f16x8*)(W2l + base);
        acc = MFMA16(A2l[ks], Bl, acc);
        acc = MFMA16(A2l[ks], Bh, acc);
        acc = MFMA16(A2h[ks], Bl, acc);
        acc = MFMA16(A2h[ks], Bh, acc);
      }
      // C: row = q*4 + r (point), col = lm -> feature c2 = nt2*16 + lm
      const int c2 = nt2*16 + lm;
      const float b2v = b2[c2];
      const int ks3 = c2 >> 5;
      const int k31 = c2 & 31;
      const int qw = k31 >> 3, jw = k31 & 7;
#pragma unroll
      for (int r = 0; r < 4; ++r) {
        const int mrow = q*4 + r;
        float h = fmaxf(acc[r]*INV16 + b2v, 0.f);
        _Float16 hi, lo;
        split_f16s(h, hi, lo);
        const int idx = (ks3*64 + qw*16 + mrow)*8 + jw;
        scr[idx] = hi;
        scr[2048 + idx] = lo;
      }
    }
    // read back this ptile's layer-3 A-fragments (same-wave DS ordering)
#pragma unroll
    for (int ks3 = 0; ks3 < 4; ++ks3) {
      const int base = (ks3*64 + l)*8;
      A3h[p][ks3] = *(const f16x8*)&scr[base];
      A3l[p][ks3] = *(const f16x8*)&scr[2048 + base];
    }
  }

  __syncthreads();   // all waves done with scr; smem becomes the B double buffer

  // ---- layer 3: LDS-staged B tiles, block-level double buffer ----
  float* outp = out + ((size_t)b*NJ + j)*KF;

  // stage tile nt0 into buffer 0 (16 B/thread x 2)
  {
    const _Float16* src = W3p + (size_t)nt0*4096;
    f16x8 s0 = *(const f16x8*)(src + t*8);
    f16x8 s1 = *(const f16x8*)(src + 2048 + t*8);
    *(f16x8*)&smem[t*8] = s0;
    *(f16x8*)&smem[2048 + t*8] = s1;
  }
  __syncthreads();

  for (int k = 0; k < NT_PER; ++k) {
    const int nt = nt0 + k;
    const int cur = (k & 1)*4096;
    const int nxt = cur ^ 4096;
    // prefetch tile k+1 to registers (latency overlaps this tile's MFMAs)
    f16x8 s0, s1;
    const int have_next = (k + 1 < NT_PER);
    if (have_next) {
      const _Float16* src = W3p + (size_t)(nt+1)*4096;
      s0 = *(const f16x8*)(src + t*8);
      s1 = *(const f16x8*)(src + 2048 + t*8);
    }
    // consume current buffer
    f16x8 B[2][4];
#pragma unroll
    for (int lev = 0; lev < 2; ++lev)
#pragma unroll
      for (int ks = 0; ks < 4; ++ks)
        B[lev][ks] = *(const f16x8*)&smem[cur + ((lev*4 + ks)*64 + l)*8];
    l3_body(A3h, A3l, B, nt, l, b3, outp);
    // commit prefetch to the other buffer, then barrier for visibility
    if (have_next) {
      *(f16x8*)&smem[nxt + t*8] = s0;
      *(f16x8*)&smem[nxt + 2048 + t*8] = s1;
    }
    __syncthreads();
  }
}

// ---------------- pinv / update / loss (verified) ----------------
__global__ void pinv_kernel(const float* __restrict__ feats, const float* __restrict__ dt,
                            float* __restrict__ pinv) {
  int b = blockIdx.x, t = threadIdx.x;
  const float* f0 = feats + (size_t)b*7*KF;
  const float* fj = f0 + KF;
  float idt[6];
#pragma unroll
  for (int i = 0; i < 6; ++i) idt[i] = 1.f / dt[i];
  float H[21];
#pragma unroll
  for (int i = 0; i < 21; ++i) H[i] = 0.f;
  for (int k = t; k < KF; k += 256) {
    float f0k = f0[k];
    float Jk[6];
#pragma unroll
    for (int i = 0; i < 6; ++i) Jk[i] = (f0k - fj[i*KF + k]) * idt[i];
    int idx = 0;
#pragma unroll
    for (int i = 0; i < 6; ++i)
#pragma unroll
      for (int jj = i; jj < 6; ++jj) H[idx++] += Jk[i]*Jk[jj];
  }
  __shared__ float red[256*21];
#pragma unroll
  for (int i = 0; i < 21; ++i) red[t*21+i] = H[i];
  __syncthreads();
  for (int s = 128; s > 0; s >>= 1) {
    if (t < s)
      for (int i = 0; i < 21; ++i) red[t*21+i] += red[(t+s)*21+i];
    __syncthreads();
  }
  __shared__ float s_hinv[36];
  if (t == 0) {
    double A[6][12];
    int idx = 0;
    for (int i = 0; i < 6; ++i)
      for (int jj = i; jj < 6; ++jj) { A[i][jj] = red[idx]; A[jj][i] = red[idx]; idx++; }
    for (int i = 0; i < 6; ++i)
      for (int jj = 0; jj < 6; ++jj) A[i][6+jj] = (i == jj) ? 1.0 : 0.0;
    for (int col = 0; col < 6; ++col) {
      int piv = col; double best = fabs(A[col][col]);
      for (int r2 = col+1; r2 < 6; ++r2) {
        double v = fabs(A[r2][col]);
        if (v > best) { best = v; piv = r2; }
      }
      if (piv != col)
        for (int jj = 0; jj < 12; ++jj) { double tmp = A[col][jj]; A[col][jj] = A[piv][jj]; A[piv][jj] = tmp; }
      double inv = 1.0 / A[col][col];
      for (int jj = 0; jj < 12; ++jj) A[col][jj] *= inv;
      for (int r2 = 0; r2 < 6; ++r2) if (r2 != col) {
        double f = A[r2][col];
        for (int jj = 0; jj < 12; ++jj) A[r2][jj] -= f * A[col][jj];
      }
    }
    for (int i = 0; i < 6; ++i)
      for (int jj = 0; jj < 6; ++jj) s_hinv[i*6+jj] = (float)A[i][6+jj];
  }
  __syncthreads();
  for (int k = t; k < KF; k += 256) {
    float f0k = f0[k];
    float Jk[6];
#pragma unroll
    for (int i = 0; i < 6; ++i) Jk[i] = (f0k - fj[i*KF + k]) * idt[i];
#pragma unroll
    for (int i = 0; i < 6; ++i) {
      float s = 0.f;
#pragma unroll
      for (int jj = 0; jj < 6; ++jj) s += s_hinv[i*6+jj] * Jk[jj];
      pinv[((size_t)b*6 + i)*KF + k] = s;
    }
  }
}

__global__ void update_kernel(const float* __restrict__ feats, const float* __restrict__ f1,
                              const float* __restrict__ pinv, float* __restrict__ g_buf,
                              const float* __restrict__ W1, const float* __restrict__ b1,
                              float* __restrict__ W1effL, float* __restrict__ b1effL,
                              float* __restrict__ f1r, float* __restrict__ r_out,
                              const float* __restrict__ mean_tgt, const float* __restrict__ mean_src,
                              float* __restrict__ est_g, int final_it) {
  int b = blockIdx.x, t = threadIdx.x;
  const float* f0  = feats + (size_t)b*7*KF;
  const float* f1b = f1 + (size_t)b*KF;
  float acc[6] = {0.f,0.f,0.f,0.f,0.f,0.f};
  for (int k = t; k < KF; k += 256) {
    float r = f1b[k] - f0[k];
    r_out[(size_t)b*KF + k] = r;
#pragma unroll
    for (int i = 0; i < 6; ++i) acc[i] += pinv[((size_t)b*6+i)*KF + k] * r;
  }
  __shared__ float red[256*6];
#pragma unroll
  for (int i = 0; i < 6; ++i) red[t*6+i] = acc[i];
  __syncthreads();
  for (int s = 128; s > 0; s >>= 1) {
    if (t < s)
      for (int i = 0; i < 6; ++i) red[t*6+i] += red[(t+s)*6+i];
    __syncthreads();
  }
  __shared__ float s_g[16];
  if (t == 0) {
    float dx[6];
#pragma unroll
    for (int i = 0; i < 6; ++i) dx[i] = -red[i];
    float R[9], p[3];
    se3_exp_dev(dx, R, p);
    float* g = g_buf + b*16;
    float gn[16];
    for (int r2 = 0; r2 < 3; ++r2)
      for (int c = 0; c < 4; ++c)
        gn[r2*4+c] = R[r2*3+0]*g[c] + R[r2*3+1]*g[4+c] + R[r2*3+2]*g[8+c] + p[r2]*g[12+c];
    gn[12] = 0.f; gn[13] = 0.f; gn[14] = 0.f; gn[15] = 1.f;
    for (int i = 0; i < 16; ++i) { g[i] = gn[i]; s_g[i] = gn[i]; }
    if (final_it) {
      const float* p0m = mean_tgt + b*3;
      const float* p1m = mean_src + b*3;
      float* e = est_g + b*12;
      for (int r2 = 0; r2 < 3; ++r2) {
        e[r2*4+0] = gn[r2*4+0];
        e[r2*4+1] = gn[r2*4+1];
        e[r2*4+2] = gn[r2*4+2];
        e[r2*4+3] = gn[r2*4+3]
                  - (gn[r2*4+0]*p1m[0] + gn[r2*4+1]*p1m[1] + gn[r2*4+2]*p1m[2])
                  + p0m[r2];
      }
    }
  }
  __syncthreads();
  if (!final_it) {
    for (int i = t; i < 192; i += 256) {
      int d = i >> 6, c = i & 63;
      W1effL[b*192 + i] = s_g[0*4+d]*W1[c] + s_g[1*4+d]*W1[64+c] + s_g[2*4+d]*W1[128+c];
    }
    for (int i = t; i < 64; i += 256)
      b1effL[b*64 + i] = b1[i] + s_g[3]*W1[i] + s_g[7]*W1[64+i] + s_g[11]*W1[128+i];
    for (int k = t; k < KF; k += 256) f1r[(size_t)b*KF + k] = -INFINITY;
  }
}

__global__ void loss_kernel(const float* __restrict__ p_src, const float* __restrict__ est_g,
                            const float* __restrict__ igt_inv, float* __restrict__ loss_out) {
  int b = blockIdx.y, tile = blockIdx.x, t = threadIdx.x;
  int n = tile*256 + t;
  const float* e = est_g + b*12;
  const float* v = igt_inv + b*12;
  const float* p = p_src + ((size_t)b*NPTS + n)*3;
  float px = p[0], py = p[1], pz = p[2];
  float s = 0.f;
#pragma unroll
  for (int r2 = 0; r2 < 3; ++r2) {
    float d1 = e[r2*4+0]*px + e[r2*4+1]*py + e[r2*4+2]*pz + e[r2*4+3];
    float d2 = v[r2*4+0]*px + v[r2*4+1]*py + v[r2*4+2]*pz + v[r2*4+3];
    s += fabsf(d1 - d2);
  }
  __shared__ float red[256];
  red[t] = s;
  __syncthreads();
  for (int st = 128; st > 0; st >>= 1) {
    if (t < st) red[t] += red[t+st];
    __syncthreads();
  }
  if (t == 0) atomicAdd(loss_out, red[0] * (1.f/((float)BATCH*NPTS*3)));
}

// ---------------- launcher ----------------
extern "C" void kernel_launch(void* const* d_in, const int* in_sizes, int n_in,
                              void* d_out, int out_size, void* d_ws, size_t ws_size,
                              hipStream_t stream) {
  const float* p_src     = (const float*)d_in[0];
  const float* p_tgt     = (const float*)d_in[1];
  const float* igt_twist = (const float*)d_in[2];
  const float* dt        = (const float*)d_in[3];
  const float* W1        = (const float*)d_in[4];
  const float* b1        = (const float*)d_in[5];
  const float* W2        = (const float*)d_in[6];
  const float* b2        = (const float*)d_in[7];
  const float* W3        = (const float*)d_in[8];
  const float* b3        = (const float*)d_in[9];
  float* out = (float*)d_out;

  float* ws = (float*)d_ws;
  float* mean_tgt = ws;  ws += 32;   // BATCH*3 used
  float* mean_src = ws;  ws += 32;
  float* W1eff7   = ws;  ws += 7*192;
  float* b1eff7   = ws;  ws += 7*64;
  float* feats    = ws;  ws += BATCH*7*KF;
  float* W1effL   = ws;  ws += BATCH*192;
  float* b1effL   = ws;  ws += BATCH*64;
  float* f1       = ws;  ws += BATCH*KF;
  float* g_buf    = ws;  ws += BATCH*16;
  float* pinvb    = ws;  ws += BATCH*6*KF;
  float* igt_inv  = ws;  ws += 96;   // BATCH*12
  float* est_g    = ws;  ws += 96;   // BATCH*12
  _Float16* W2h = (_Float16*)ws;  ws += 8192/2;
  _Float16* W2l = (_Float16*)ws;  ws += 8192/2;
  _Float16* W3p = (_Float16*)ws;  ws += 262144/2;   // 64 tiles x 4096 f16 (hi+lo)

  float* r_out    = out;
  float* loss_out = out + BATCH*KF;

  means_kernel<<<dim3(BATCH*2), 256, 0, stream>>>(p_tgt, p_src, mean_tgt, mean_src);
  setup_kernel<<<1, 256, 0, stream>>>(dt, W1, b1, igt_twist, feats, f1, W1eff7, b1eff7,
                                      W1effL, b1effL, g_buf, igt_inv, loss_out);
  pack_w2_kernel<<<dim3(8192/256), 256, 0, stream>>>(W2, W2h, W2l);
  pack_w3_kernel<<<dim3(131072/256), 256, 0, stream>>>(W3, W3p);

  // f0 + 6 twist-perturbed encodes: FG=1 -> grid (16,7,8) = 896 blocks, NT_PER=64
  encode_mfma<<<dim3(NPTS/PTB, 7, BATCH), 256, 0, stream>>>(
      p_tgt, mean_tgt, W1eff7, b1eff7, W2h, W2l, W3p, b2, b3, feats, 7, 1, 0);
  pinv_kernel<<<dim3(BATCH), 256, 0, stream>>>(feats, dt, pinvb);

  for (int it = 0; it < 5; ++it) {
    // loop encode: FG=2 -> grid (16,2,8) = 256 blocks, NT_PER=32
    encode_mfma<<<dim3(NPTS/PTB, 2, BATCH), 256, 0, stream>>>(
        p_src, mean_src, W1effL, b1effL, W2h, W2l, W3p, b2, b3, f1, 1, 2, 1);
    update_kernel<<<dim3(BATCH), 256, 0, stream>>>(
        feats, f1, pinvb, g_buf, W1, b1, W1effL, b1effL, f1, r_out,
        mean_tgt, mean_src, est_g, (it == 4) ? 1 : 0);
  }
  loss_kernel<<<dim3(NPTS/256, BATCH), 256, 0, stream>>>(p_src, est_g, igt_inv, loss_out);
}

// Round 8
// 443.089 us; speedup vs baseline: 1.1219x; 1.1219x over previous
//
#include <hip/hip_runtime.h>
#include <math.h>

#define BATCH 8
#define NPTS 2048
#define KF 1024
#define PTB 128   // big encode: points per block (4 waves x 32)

typedef _Float16 f16x8 __attribute__((ext_vector_type(8)));
typedef float f32x4 __attribute__((ext_vector_type(4)));

// 16x16x32 layouts HW-verified (m89/m91/m97/m120):
//  A: lane holds A[m=lane&15][k=(lane>>4)*8+j]
//  B: lane holds B[k=(lane>>4)*8+j][n=lane&15]
//  C/D: lane,reg holds C[row=(lane>>4)*4+reg][col=lane&15]
#define MFMA16(a,b,c) __builtin_amdgcn_mfma_f32_16x16x32_f16((a),(b),(c),0,0,0)

#define FSCALE 256.0f
#define INV16  (1.0f/65536.0f)

// fp16 2-way split of (x*256); 3 products (hh, hl, lh) kept, ll dropped:
// residual <= 2^-22 * sum|A||B| -> ~4e-4 on r after GN amplification. Safe.
__device__ __forceinline__ void split_f16s(float x, _Float16& hi, _Float16& lo) {
  float xs = x * FSCALE;
  hi = (_Float16)xs;
  lo = (_Float16)(xs - (float)hi);
}

// ---------------- misc device helpers ----------------
__device__ __forceinline__ void mat3mul(const float* A, const float* Bm, float* C) {
#pragma unroll
  for (int i = 0; i < 3; ++i)
#pragma unroll
    for (int j = 0; j < 3; ++j)
      C[i*3+j] = A[i*3+0]*Bm[0*3+j] + A[i*3+1]*Bm[1*3+j] + A[i*3+2]*Bm[2*3+j];
}

__device__ void se3_exp_dev(const float* x, float* R, float* p) {
  float wx = x[0], wy = x[1], wz = x[2];
  float vx = x[3], vy = x[4], vz = x[5];
  float t2 = wx*wx + wy*wy + wz*wz;
  float t = sqrtf(t2);
  float A, Bc, Cc;
  if (t < 1e-6f) {
    A  = 1.f - t2*(1.f/6.f);
    Bc = 0.5f - t2*(1.f/24.f);
    Cc = (1.f/6.f) - t2*(1.f/120.f);
  } else {
    float s = sinf(t), c = cosf(t);
    A  = s / t;
    Bc = (1.f - c) / t2;
    Cc = (t - s) / (t2 * t);
  }
  float W[9]  = {0.f, -wz, wy,  wz, 0.f, -wx,  -wy, wx, 0.f};
  float W2[9];
  mat3mul(W, W, W2);
#pragma unroll
  for (int i = 0; i < 9; ++i) {
    float I = (i == 0 || i == 4 || i == 8) ? 1.f : 0.f;
    R[i] = I + A*W[i] + Bc*W2[i];
  }
  float V[9];
#pragma unroll
  for (int i = 0; i < 9; ++i) {
    float I = (i == 0 || i == 4 || i == 8) ? 1.f : 0.f;
    V[i] = I + Bc*W[i] + Cc*W2[i];
  }
  p[0] = V[0]*vx + V[1]*vy + V[2]*vz;
  p[1] = V[3]*vx + V[4]*vy + V[5]*vz;
  p[2] = V[6]*vx + V[7]*vy + V[8]*vz;
}

__device__ __forceinline__ void atomicMaxFloat(float* addr, float val) {
  if (__float_as_uint(val) >> 31) {
    atomicMin((unsigned int*)addr, __float_as_uint(val));
  } else {
    atomicMax((int*)addr, __float_as_int(val));
  }
}

// ---------------- small kernels (verified) ----------------
__global__ void means_kernel(const float* __restrict__ tgt, const float* __restrict__ src,
                             float* __restrict__ mean_tgt, float* __restrict__ mean_src) {
  int which = blockIdx.x & 1, b = blockIdx.x >> 1;
  const float* p = (which ? src : tgt) + (size_t)b*NPTS*3;
  float* m = (which ? mean_src : mean_tgt) + b*3;
  int t = threadIdx.x;
  float s0 = 0.f, s1 = 0.f, s2 = 0.f;
  for (int i = t; i < NPTS; i += 256) {
    s0 += p[i*3+0]; s1 += p[i*3+1]; s2 += p[i*3+2];
  }
  __shared__ float red[256][3];
  red[t][0] = s0; red[t][1] = s1; red[t][2] = s2;
  __syncthreads();
  for (int s = 128; s > 0; s >>= 1) {
    if (t < s) { red[t][0] += red[t+s][0]; red[t][1] += red[t+s][1]; red[t][2] += red[t+s][2]; }
    __syncthreads();
  }
  if (t == 0) {
    m[0] = red[0][0] * (1.f/NPTS);
    m[1] = red[0][1] * (1.f/NPTS);
    m[2] = red[0][2] * (1.f/NPTS);
  }
}

__global__ void setup_kernel(const float* __restrict__ dt, const float* __restrict__ W1,
                             const float* __restrict__ b1, const float* __restrict__ igt_twist,
                             float* __restrict__ feats, float* __restrict__ f1,
                             float* __restrict__ W1eff7, float* __restrict__ b1eff7,
                             float* __restrict__ W1effL, float* __restrict__ b1effL,
                             float* __restrict__ g_buf, float* __restrict__ igt_inv,
                             float* __restrict__ loss_out) {
  int t = threadIdx.x;
  for (int i = t; i < BATCH*7*KF; i += 256) feats[i] = -INFINITY;
  for (int i = t; i < BATCH*KF;   i += 256) f1[i]    = -INFINITY;
  for (int i = t; i < BATCH*192;  i += 256) W1effL[i] = W1[i % 192];
  for (int i = t; i < BATCH*64;   i += 256) b1effL[i] = b1[i & 63];
  if (t < 192) W1eff7[t] = W1[t];
  if (t < 64)  b1eff7[t] = b1[t];
  if (t < BATCH*16) {
    int i = t & 15;
    g_buf[t] = (i == 0 || i == 5 || i == 10 || i == 15) ? 1.f : 0.f;
  }
  if (t == 0) *loss_out = 0.f;
  if (t < 6) {
    float tw[6] = {0.f,0.f,0.f,0.f,0.f,0.f};
    tw[t] = -dt[t];
    float R[9], tr[3];
    se3_exp_dev(tw, R, tr);
    float* Wd = W1eff7 + (t+1)*192;
    for (int d = 0; d < 3; ++d)
      for (int c = 0; c < 64; ++c)
        Wd[d*64+c] = R[0*3+d]*W1[c] + R[1*3+d]*W1[64+c] + R[2*3+d]*W1[128+c];
    float* bd = b1eff7 + (t+1)*64;
    for (int c = 0; c < 64; ++c)
      bd[c] = b1[c] + tr[0]*W1[c] + tr[1]*W1[64+c] + tr[2]*W1[128+c];
  }
  if (t >= 32 && t < 32+BATCH) {
    int b = t - 32;
    float R[9], tr[3];
    se3_exp_dev(igt_twist + b*6, R, tr);
    float* inv = igt_inv + b*12;
    for (int r = 0; r < 3; ++r) {
      inv[r*4+0] = R[0*3+r];
      inv[r*4+1] = R[1*3+r];
      inv[r*4+2] = R[2*3+r];
      inv[r*4+3] = -(R[0*3+r]*tr[0] + R[1*3+r]*tr[1] + R[2*3+r]*tr[2]);
    }
  }
}

// ---------------- weight packs (verified layouts) ----------------
// W3p: [nt][lev][ks3][lane][8], 4096 f16 (8 KB) per nt tile, linear.
__global__ void pack_w3_kernel(const float* __restrict__ W3, _Float16* __restrict__ P) {
  int i = blockIdx.x*256 + threadIdx.x;   // 128*1024
  int k = i >> 10, n = i & 1023;
  _Float16 hi, lo;
  split_f16s(W3[i], hi, lo);
  int nt = n >> 4, col = n & 15;
  int ks3 = k >> 5, rr = k & 31;
  int lane = (rr >> 3)*16 + col, jj = rr & 7;
  size_t base = (size_t)nt*4096;
  P[base + ((0*4 + ks3)*64 + lane)*8 + jj] = hi;
  P[base + ((1*4 + ks3)*64 + lane)*8 + jj] = lo;
}

__global__ void pack_w2_kernel(const float* __restrict__ W2,
                               _Float16* __restrict__ H, _Float16* __restrict__ L) {
  int i = blockIdx.x*256 + threadIdx.x;   // 64*128
  int k = i >> 7, n = i & 127;
  _Float16 hi, lo;
  split_f16s(W2[i], hi, lo);
  int nt2 = n >> 4, col = n & 15;
  int ks = k >> 5, rr = k & 31;
  int lane = (rr >> 3)*16 + col, jj = rr & 7;
  int dst = ((nt2*2 + ks)*64 + lane)*8 + jj;
  H[dst] = hi; L[dst] = lo;
}

// ---------------- shared encode pieces ----------------
__device__ __forceinline__ f32x4 zero4() {
  f32x4 z; z[0]=0.f; z[1]=0.f; z[2]=0.f; z[3]=0.f; return z;
}

// layer1 + layer2 (3-product) for one ptile; produces layer-3 A-fragments via
// per-wave LDS relayout scratch (same-wave DS ordering, no barriers).
__device__ __forceinline__ void l12_ptile(
    float px, float py, float pz,
    const float* __restrict__ w1, const float* __restrict__ bb1,
    const _Float16* __restrict__ W2h, const _Float16* __restrict__ W2l,
    const float* __restrict__ b2,
    _Float16* scr, int l, int lm, int q,
    f16x8 (&A3h)[4], f16x8 (&A3l)[4]) {
  f16x8 A2h[2], A2l[2];
#pragma unroll
  for (int ks = 0; ks < 2; ++ks) {
    const int c0 = ks*32 + q*8;
    float wa[8], wb[8], wc[8], bv[8];
    *(float4*)&wa[0] = *(const float4*)(w1 + c0);
    *(float4*)&wa[4] = *(const float4*)(w1 + c0 + 4);
    *(float4*)&wb[0] = *(const float4*)(w1 + 64 + c0);
    *(float4*)&wb[4] = *(const float4*)(w1 + 64 + c0 + 4);
    *(float4*)&wc[0] = *(const float4*)(w1 + 128 + c0);
    *(float4*)&wc[4] = *(const float4*)(w1 + 128 + c0 + 4);
    *(float4*)&bv[0] = *(const float4*)(bb1 + c0);
    *(float4*)&bv[4] = *(const float4*)(bb1 + c0 + 4);
#pragma unroll
    for (int jj = 0; jj < 8; ++jj) {
      float h = fmaf(px, wa[jj], fmaf(py, wb[jj], fmaf(pz, wc[jj], bv[jj])));
      h = fmaxf(h, 0.f);
      _Float16 hi, lo;
      split_f16s(h, hi, lo);
      A2h[ks][jj] = hi; A2l[ks][jj] = lo;
    }
  }
#pragma unroll
  for (int nt2 = 0; nt2 < 8; ++nt2) {
    f32x4 acc = zero4();
#pragma unroll
    for (int ks = 0; ks < 2; ++ks) {
      const int base = ((nt2*2 + ks)*64 + l)*8;
      const f16x8 Bh = *(const f16x8*)(W2h + base);
      const f16x8 Bl = *(const f16x8*)(W2l + base);
      acc = MFMA16(A2l[ks], Bh, acc);
      acc = MFMA16(A2h[ks], Bl, acc);
      acc = MFMA16(A2h[ks], Bh, acc);
    }
    const int c2 = nt2*16 + lm;
    const float b2v = b2[c2];
    const int ks3 = c2 >> 5;
    const int k31 = c2 & 31;
    const int qw = k31 >> 3, jw = k31 & 7;
#pragma unroll
    for (int r = 0; r < 4; ++r) {
      const int mrow = q*4 + r;
      float h = fmaxf(acc[r]*INV16 + b2v, 0.f);
      _Float16 hi, lo;
      split_f16s(h, hi, lo);
      const int idx = (ks3*64 + qw*16 + mrow)*8 + jw;
      scr[idx] = hi;
      scr[2048 + idx] = lo;
    }
  }
#pragma unroll
  for (int ks3 = 0; ks3 < 4; ++ks3) {
    const int base = (ks3*64 + l)*8;
    A3h[ks3] = *(const f16x8*)&scr[base];
    A3l[ks3] = *(const f16x8*)&scr[2048 + base];
  }
}

__device__ __forceinline__ void l3_body(
    const f16x8 (&Ah)[2][4], const f16x8 (&Al)[2][4],
    const f16x8 (&B)[2][4],
    int nt, int l, const float* __restrict__ b3, float* __restrict__ outp) {
  f32x4 a[2] = {zero4(), zero4()};
#pragma unroll
  for (int ks = 0; ks < 4; ++ks) {
#pragma unroll
    for (int p = 0; p < 2; ++p) a[p] = MFMA16(Al[p][ks], B[0][ks], a[p]);  // l*h
#pragma unroll
    for (int p = 0; p < 2; ++p) a[p] = MFMA16(Ah[p][ks], B[1][ks], a[p]);  // h*l
#pragma unroll
    for (int p = 0; p < 2; ++p) a[p] = MFMA16(Ah[p][ks], B[0][ks], a[p]);  // h*h
  }
  float mx = -INFINITY;
#pragma unroll
  for (int p = 0; p < 2; ++p)
#pragma unroll
    for (int r = 0; r < 4; ++r) mx = fmaxf(mx, a[p][r]);
  mx = fmaxf(mx, __shfl_xor(mx, 16, 64));
  mx = fmaxf(mx, __shfl_xor(mx, 32, 64));
  if (l < 16) {
    int feat = nt*16 + (l & 15);
    atomicMaxFloat(outp + feat, mx*INV16 + b3[feat]);
  }
}

// ---------------- BIG encode (f0 + 6 twists): R6 structure, 3 products ----------------
__global__ __launch_bounds__(256, 3) void encode_mfma(
    const float* __restrict__ pts, const float* __restrict__ mean,
    const float* __restrict__ W1e, const float* __restrict__ b1e,
    const _Float16* __restrict__ W2h, const _Float16* __restrict__ W2l,
    const _Float16* __restrict__ W3p,
    const float* __restrict__ b2, const float* __restrict__ b3,
    float* __restrict__ out, int NJ) {
  const int t = threadIdx.x;
  const int w = t >> 6, l = t & 63;
  const int lm = l & 15, q = l >> 4;
  const int pblk = blockIdx.x;
  const int j = blockIdx.y;
  const int b = blockIdx.z;

  __shared__ __align__(16) _Float16 smem[16384];   // 32 KB

  const int ptbase = pblk*PTB + w*32;
  float mx0 = mean[b*3+0], my0 = mean[b*3+1], mz0 = mean[b*3+2];
  const float* w1 = W1e + j*192;
  const float* bb1 = b1e + j*64;

  f16x8 A3h[2][4], A3l[2][4];
  _Float16* scr = smem + w*4096;
#pragma unroll
  for (int p = 0; p < 2; ++p) {
    const float* pp = pts + ((size_t)b*NPTS + ptbase + p*16 + lm)*3;
    l12_ptile(pp[0]-mx0, pp[1]-my0, pp[2]-mz0, w1, bb1, W2h, W2l, b2,
              scr, l, lm, q, A3h[p], A3l[p]);
  }

  __syncthreads();   // scr done; smem becomes B double buffer

  float* outp = out + ((size_t)b*NJ + j)*KF;
  {
    const _Float16* src = W3p;   // nt0 = 0 (big encode covers all 64 tiles)
    f16x8 s0 = *(const f16x8*)(src + t*8);
    f16x8 s1 = *(const f16x8*)(src + 2048 + t*8);
    *(f16x8*)&smem[t*8] = s0;
    *(f16x8*)&smem[2048 + t*8] = s1;
  }
  __syncthreads();

  for (int k = 0; k < 64; ++k) {
    const int cur = (k & 1)*4096;
    const int nxt = cur ^ 4096;
    f16x8 s0, s1;
    const int have_next = (k + 1 < 64);
    if (have_next) {
      const _Float16* src = W3p + (size_t)(k+1)*4096;
      s0 = *(const f16x8*)(src + t*8);
      s1 = *(const f16x8*)(src + 2048 + t*8);
    }
    f16x8 B[2][4];
#pragma unroll
    for (int lev = 0; lev < 2; ++lev)
#pragma unroll
      for (int ks = 0; ks < 4; ++ks)
        B[lev][ks] = *(const f16x8*)&smem[cur + ((lev*4 + ks)*64 + l)*8];
    l3_body(A3h, A3l, B, k, l, b3, outp);
    if (have_next) {
      *(f16x8*)&smem[nxt + t*8] = s0;
      *(f16x8*)&smem[nxt + 2048 + t*8] = s1;
    }
    __syncthreads();
  }
}

// ---------------- LOOP encode phase A: layers 1-2, store A3 fragments ----------------
// grid (16,1,8) x 256: wave w covers ptiles (pblk*4+w)*2 .. +1
__global__ __launch_bounds__(256, 3) void encode_phA(
    const float* __restrict__ pts, const float* __restrict__ mean,
    const float* __restrict__ W1e, const float* __restrict__ b1e,
    const _Float16* __restrict__ W2h, const _Float16* __restrict__ W2l,
    const float* __restrict__ b2, _Float16* __restrict__ A3buf) {
  const int t = threadIdx.x;
  const int w = t >> 6, l = t & 63;
  const int lm = l & 15, q = l >> 4;
  const int pblk = blockIdx.x;
  const int b = blockIdx.z;

  __shared__ __align__(16) _Float16 smem[16384];

  const int ptbase = pblk*PTB + w*32;
  float mx0 = mean[b*3+0], my0 = mean[b*3+1], mz0 = mean[b*3+2];
  const float* w1 = W1e + b*192;
  const float* bb1 = b1e + b*64;

  _Float16* scr = smem + w*4096;
#pragma unroll
  for (int p = 0; p < 2; ++p) {
    const float* pp = pts + ((size_t)b*NPTS + ptbase + p*16 + lm)*3;
    f16x8 A3h[4], A3l[4];
    l12_ptile(pp[0]-mx0, pp[1]-my0, pp[2]-mz0, w1, bb1, W2h, W2l, b2,
              scr, l, lm, q, A3h, A3l);
    const int ptile = (pblk*4 + w)*2 + p;
    _Float16* dst = A3buf + ((size_t)(b*128 + ptile)*8)*512;
#pragma unroll
    for (int ks = 0; ks < 4; ++ks) {
      *(f16x8*)(dst + (size_t)(0*4 + ks)*512 + l*8) = A3h[ks];
      *(f16x8*)(dst + (size_t)(1*4 + ks)*512 + l*8) = A3l[ks];
    }
  }
}

// ---------------- LOOP encode phase B: stream A, B in registers ----------------
__device__ __forceinline__ void load_A(f16x8 (&A)[2][4],
    const _Float16* __restrict__ A3buf, int bpt, int l) {
#pragma unroll
  for (int lev = 0; lev < 2; ++lev)
#pragma unroll
    for (int ks = 0; ks < 4; ++ks)
      A[lev][ks] = *(const f16x8*)(A3buf + ((size_t)bpt*8 + lev*4 + ks)*512 + l*8);
}

__device__ __forceinline__ void phb_step(
    const f16x8 (&A)[2][4], const f16x8 (&B)[2][2][4], f32x4 (&vmax)[2]) {
  f32x4 acc0 = zero4(), acc1 = zero4();
#pragma unroll
  for (int ks = 0; ks < 4; ++ks) {
    acc0 = MFMA16(A[1][ks], B[0][0][ks], acc0);   // l*h
    acc1 = MFMA16(A[1][ks], B[1][0][ks], acc1);
    acc0 = MFMA16(A[0][ks], B[0][1][ks], acc0);   // h*l
    acc1 = MFMA16(A[0][ks], B[1][1][ks], acc1);
    acc0 = MFMA16(A[0][ks], B[0][0][ks], acc0);   // h*h
    acc1 = MFMA16(A[0][ks], B[1][0][ks], acc1);
  }
#pragma unroll
  for (int r = 0; r < 4; ++r) {
    vmax[0][r] = fmaxf(vmax[0][r], acc0[r]);
    vmax[1][r] = fmaxf(vmax[1][r], acc1[r]);
  }
}

// grid (32, 4, 8), 128 thr = 2 waves; wave owns 2 nt tiles x 16 ptiles.
// No LDS, no barriers; depth-2 register A-prefetch; one atomic per tile at end.
__global__ __launch_bounds__(128, 3) void encode_phB(
    const _Float16* __restrict__ A3buf, const _Float16* __restrict__ W3p,
    const float* __restrict__ b3, float* __restrict__ out) {
  const int t = threadIdx.x, w = t >> 6, l = t & 63, lm = l & 15;
  const int nb = blockIdx.x, ph = blockIdx.y, b = blockIdx.z;
  const int pt0 = (ph*2 + w)*16;

  f16x8 B[2][2][4];   // [tile][lev][ks]
#pragma unroll
  for (int tile = 0; tile < 2; ++tile) {
    const _Float16* wp = W3p + (size_t)(nb*2 + tile)*4096;
#pragma unroll
    for (int lev = 0; lev < 2; ++lev)
#pragma unroll
      for (int ks = 0; ks < 4; ++ks)
        B[tile][lev][ks] = *(const f16x8*)(wp + ((lev*4 + ks)*64 + l)*8);
  }
  f32x4 vmax[2];
#pragma unroll
  for (int r = 0; r < 4; ++r) { vmax[0][r] = -INFINITY; vmax[1][r] = -INFINITY; }

  const int base = b*128;
  f16x8 A0[2][4], A1[2][4];
  load_A(A0, A3buf, base + pt0, l);
  for (int i = 0; i < 16; i += 2) {
    load_A(A1, A3buf, base + pt0 + i + 1, l);
    phb_step(A0, B, vmax);
    if (i + 2 < 16) load_A(A0, A3buf, base + pt0 + i + 2, l);
    phb_step(A1, B, vmax);
  }
#pragma unroll
  for (int tile = 0; tile < 2; ++tile) {
    float m = fmaxf(fmaxf(vmax[tile][0], vmax[tile][1]),
                    fmaxf(vmax[tile][2], vmax[tile][3]));
    m = fmaxf(m, __shfl_xor(m, 16, 64));
    m = fmaxf(m, __shfl_xor(m, 32, 64));
    if (l < 16) {
      int feat = (nb*2 + tile)*16 + lm;
      atomicMaxFloat(out + (size_t)b*KF + feat, m*INV16 + b3[feat]);
    }
  }
}

// ---------------- pinv / update / loss (verified) ----------------
__global__ void pinv_kernel(const float* __restrict__ feats, const float* __restrict__ dt,
                            float* __restrict__ pinv) {
  int b = blockIdx.x, t = threadIdx.x;
  const float* f0 = feats + (size_t)b*7*KF;
  const float* fj = f0 + KF;
  float idt[6];
#pragma unroll
  for (int i = 0; i < 6; ++i) idt[i] = 1.f / dt[i];
  float H[21];
#pragma unroll
  for (int i = 0; i < 21; ++i) H[i] = 0.f;
  for (int k = t; k < KF; k += 256) {
    float f0k = f0[k];
    float Jk[6];
#pragma unroll
    for (int i = 0; i < 6; ++i) Jk[i] = (f0k - fj[i*KF + k]) * idt[i];
    int idx = 0;
#pragma unroll
    for (int i = 0; i < 6; ++i)
#pragma unroll
      for (int jj = i; jj < 6; ++jj) H[idx++] += Jk[i]*Jk[jj];
  }
  __shared__ float red[256*21];
#pragma unroll
  for (int i = 0; i < 21; ++i) red[t*21+i] = H[i];
  __syncthreads();
  for (int s = 128; s > 0; s >>= 1) {
    if (t < s)
      for (int i = 0; i < 21; ++i) red[t*21+i] += red[(t+s)*21+i];
    __syncthreads();
  }
  __shared__ float s_hinv[36];
  if (t == 0) {
    double A[6][12];
    int idx = 0;
    for (int i = 0; i < 6; ++i)
      for (int jj = i; jj < 6; ++jj) { A[i][jj] = red[idx]; A[jj][i] = red[idx]; idx++; }
    for (int i = 0; i < 6; ++i)
      for (int jj = 0; jj < 6; ++jj) A[i][6+jj] = (i == jj) ? 1.0 : 0.0;
    for (int col = 0; col < 6; ++col) {
      int piv = col; double best = fabs(A[col][col]);
      for (int r2 = col+1; r2 < 6; ++r2) {
        double v = fabs(A[r2][col]);
        if (v > best) { best = v; piv = r2; }
      }
      if (piv != col)
        for (int jj = 0; jj < 12; ++jj) { double tmp = A[col][jj]; A[col][jj] = A[piv][jj]; A[piv][jj] = tmp; }
      double inv = 1.0 / A[col][col];
      for (int jj = 0; jj < 12; ++jj) A[col][jj] *= inv;
      for (int r2 = 0; r2 < 6; ++r2) if (r2 != col) {
        double f = A[r2][col];
        for (int jj = 0; jj < 12; ++jj) A[r2][jj] -= f * A[col][jj];
      }
    }
    for (int i = 0; i < 6; ++i)
      for (int jj = 0; jj < 6; ++jj) s_hinv[i*6+jj] = (float)A[i][6+jj];
  }
  __syncthreads();
  for (int k = t; k < KF; k += 256) {
    float f0k = f0[k];
    float Jk[6];
#pragma unroll
    for (int i = 0; i < 6; ++i) Jk[i] = (f0k - fj[i*KF + k]) * idt[i];
#pragma unroll
    for (int i = 0; i < 6; ++i) {
      float s = 0.f;
#pragma unroll
      for (int jj = 0; jj < 6; ++jj) s += s_hinv[i*6+jj] * Jk[jj];
      pinv[((size_t)b*6 + i)*KF + k] = s;
    }
  }
}

__global__ void update_kernel(const float* __restrict__ feats, const float* __restrict__ f1,
                              const float* __restrict__ pinv, float* __restrict__ g_buf,
                              const float* __restrict__ W1, const float* __restrict__ b1,
                              float* __restrict__ W1effL, float* __restrict__ b1effL,
                              float* __restrict__ f1r, float* __restrict__ r_out,
                              const float* __restrict__ mean_tgt, const float* __restrict__ mean_src,
                              float* __restrict__ est_g, int final_it) {
  int b = blockIdx.x, t = threadIdx.x;
  const float* f0  = feats + (size_t)b*7*KF;
  const float* f1b = f1 + (size_t)b*KF;
  float acc[6] = {0.f,0.f,0.f,0.f,0.f,0.f};
  for (int k = t; k < KF; k += 256) {
    float r = f1b[k] - f0[k];
    r_out[(size_t)b*KF + k] = r;
#pragma unroll
    for (int i = 0; i < 6; ++i) acc[i] += pinv[((size_t)b*6+i)*KF + k] * r;
  }
  __shared__ float red[256*6];
#pragma unroll
  for (int i = 0; i < 6; ++i) red[t*6+i] = acc[i];
  __syncthreads();
  for (int s = 128; s > 0; s >>= 1) {
    if (t < s)
      for (int i = 0; i < 6; ++i) red[t*6+i] += red[(t+s)*6+i];
    __syncthreads();
  }
  __shared__ float s_g[16];
  if (t == 0) {
    float dx[6];
#pragma unroll
    for (int i = 0; i < 6; ++i) dx[i] = -red[i];
    float R[9], p[3];
    se3_exp_dev(dx, R, p);
    float* g = g_buf + b*16;
    float gn[16];
    for (int r2 = 0; r2 < 3; ++r2)
      for (int c = 0; c < 4; ++c)
        gn[r2*4+c] = R[r2*3+0]*g[c] + R[r2*3+1]*g[4+c] + R[r2*3+2]*g[8+c] + p[r2]*g[12+c];
    gn[12] = 0.f; gn[13] = 0.f; gn[14] = 0.f; gn[15] = 1.f;
    for (int i = 0; i < 16; ++i) { g[i] = gn[i]; s_g[i] = gn[i]; }
    if (final_it) {
      const float* p0m = mean_tgt + b*3;
      const float* p1m = mean_src + b*3;
      float* e = est_g + b*12;
      for (int r2 = 0; r2 < 3; ++r2) {
        e[r2*4+0] = gn[r2*4+0];
        e[r2*4+1] = gn[r2*4+1];
        e[r2*4+2] = gn[r2*4+2];
        e[r2*4+3] = gn[r2*4+3]
                  - (gn[r2*4+0]*p1m[0] + gn[r2*4+1]*p1m[1] + gn[r2*4+2]*p1m[2])
                  + p0m[r2];
      }
    }
  }
  __syncthreads();
  if (!final_it) {
    for (int i = t; i < 192; i += 256) {
      int d = i >> 6, c = i & 63;
      W1effL[b*192 + i] = s_g[0*4+d]*W1[c] + s_g[1*4+d]*W1[64+c] + s_g[2*4+d]*W1[128+c];
    }
    for (int i = t; i < 64; i += 256)
      b1effL[b*64 + i] = b1[i] + s_g[3]*W1[i] + s_g[7]*W1[64+i] + s_g[11]*W1[128+i];
    for (int k = t; k < KF; k += 256) f1r[(size_t)b*KF + k] = -INFINITY;
  }
}

__global__ void loss_kernel(const float* __restrict__ p_src, const float* __restrict__ est_g,
                            const float* __restrict__ igt_inv, float* __restrict__ loss_out) {
  int b = blockIdx.y, tile = blockIdx.x, t = threadIdx.x;
  int n = tile*256 + t;
  const float* e = est_g + b*12;
  const float* v = igt_inv + b*12;
  const float* p = p_src + ((size_t)b*NPTS + n)*3;
  float px = p[0], py = p[1], pz = p[2];
  float s = 0.f;
#pragma unroll
  for (int r2 = 0; r2 < 3; ++r2) {
    float d1 = e[r2*4+0]*px + e[r2*4+1]*py + e[r2*4+2]*pz + e[r2*4+3];
    float d2 = v[r2*4+0]*px + v[r2*4+1]*py + v[r2*4+2]*pz + v[r2*4+3];
    s += fabsf(d1 - d2);
  }
  __shared__ float red[256];
  red[t] = s;
  __syncthreads();
  for (int st = 128; st > 0; st >>= 1) {
    if (t < st) red[t] += red[t+st];
    __syncthreads();
  }
  if (t == 0) atomicAdd(loss_out, red[0] * (1.f/((float)BATCH*NPTS*3)));
}

// ---------------- launcher ----------------
extern "C" void kernel_launch(void* const* d_in, const int* in_sizes, int n_in,
                              void* d_out, int out_size, void* d_ws, size_t ws_size,
                              hipStream_t stream) {
  const float* p_src     = (const float*)d_in[0];
  const float* p_tgt     = (const float*)d_in[1];
  const float* igt_twist = (const float*)d_in[2];
  const float* dt        = (const float*)d_in[3];
  const float* W1        = (const float*)d_in[4];
  const float* b1        = (const float*)d_in[5];
  const float* W2        = (const float*)d_in[6];
  const float* b2        = (const float*)d_in[7];
  const float* W3        = (const float*)d_in[8];
  const float* b3        = (const float*)d_in[9];
  float* out = (float*)d_out;

  float* ws = (float*)d_ws;
  float* mean_tgt = ws;  ws += 32;   // BATCH*3 used
  float* mean_src = ws;  ws += 32;
  float* W1eff7   = ws;  ws += 7*192;
  float* b1eff7   = ws;  ws += 7*64;
  float* feats    = ws;  ws += BATCH*7*KF;
  float* W1effL   = ws;  ws += BATCH*192;
  float* b1effL   = ws;  ws += BATCH*64;
  float* f1       = ws;  ws += BATCH*KF;
  float* g_buf    = ws;  ws += BATCH*16;
  float* pinvb    = ws;  ws += BATCH*6*KF;
  float* igt_inv  = ws;  ws += 96;   // BATCH*12
  float* est_g    = ws;  ws += 96;   // BATCH*12
  _Float16* W2h = (_Float16*)ws;  ws += 8192/2;
  _Float16* W2l = (_Float16*)ws;  ws += 8192/2;
  _Float16* W3p = (_Float16*)ws;  ws += 262144/2;            // 64 tiles x 8 KB
  _Float16* A3buf = (_Float16*)ws;  ws += BATCH*128*4096/2;  // 8.4 MB A3 fragments

  float* r_out    = out;
  float* loss_out = out + BATCH*KF;

  means_kernel<<<dim3(BATCH*2), 256, 0, stream>>>(p_tgt, p_src, mean_tgt, mean_src);
  setup_kernel<<<1, 256, 0, stream>>>(dt, W1, b1, igt_twist, feats, f1, W1eff7, b1eff7,
                                      W1effL, b1effL, g_buf, igt_inv, loss_out);
  pack_w2_kernel<<<dim3(8192/256), 256, 0, stream>>>(W2, W2h, W2l);
  pack_w3_kernel<<<dim3(131072/256), 256, 0, stream>>>(W3, W3p);

  // f0 + 6 twist-perturbed encodes: grid (16,7,8)
  encode_mfma<<<dim3(NPTS/PTB, 7, BATCH), 256, 0, stream>>>(
      p_tgt, mean_tgt, W1eff7, b1eff7, W2h, W2l, W3p, b2, b3, feats, 7);
  pinv_kernel<<<dim3(BATCH), 256, 0, stream>>>(feats, dt, pinvb);

  for (int it = 0; it < 5; ++it) {
    encode_phA<<<dim3(NPTS/PTB, 1, BATCH), 256, 0, stream>>>(
        p_src, mean_src, W1effL, b1effL, W2h, W2l, b2, A3buf);
    encode_phB<<<dim3(32, 4, BATCH), 128, 0, stream>>>(A3buf, W3p, b3, f1);
    update_kernel<<<dim3(BATCH), 256, 0, stream>>>(
        feats, f1, pinvb, g_buf, W1, b1, W1effL, b1effL, f1, r_out,
        mean_tgt, mean_src, est_g, (it == 4) ? 1 : 0);
  }
  loss_kernel<<<dim3(NPTS/256, BATCH), 256, 0, stream>>>(p_src, est_g, igt_inv, loss_out);
}